// Round 3
// baseline (1109.298 us; speedup 1.0000x reference)
//
#include <hip/hip_runtime.h>
#include <cstdint>
#include <cstddef>

// SAGE-LSTM R14: R13's 8-wave decomposition + R11's staged prefetch + packed h-write.
// R13 post-mortem: occupancy 2x as designed (39%) but dur regressed 270->322us:
//  (a) global->reg gather latency (~600-900cyc, 51MB buffer scattered over 8 L2s)
//      sat serially in each of 16 steps (R11 hid it with staging; R13 didn't).
//  (b) scalar ushort h-writes -> 6.4M bank conflicts (4-way: same-dword col pairs
//      + l4 bank aliasing).
// R14: per-step 32KB xu staged into LDS dbuf via global_load_lds (issued 1 step
// ahead, drained by the step-end barrier -> latency hides under MFMA+cell);
// h single-buffered 8KB (LDS 74KB -> 2 blocks/CU at (512,4)); h-write packed to
// u32 by even lanes via shfl_xor (2-way = free). acc-init = conflict-free
// ds_read_b64 from staged rows.

constexpr int IN  = 128;
constexpr int DEG = 16;

typedef short bf16x8 __attribute__((ext_vector_type(8)));
typedef float f32x4  __attribute__((ext_vector_type(4)));
typedef float f32x16 __attribute__((ext_vector_type(16)));
typedef unsigned int u32x4 __attribute__((ext_vector_type(4)));
typedef unsigned int u32x2 __attribute__((ext_vector_type(2)));

__device__ __forceinline__ float fsigmoid(float x) {
    float e = __expf(-x);
    return __builtin_amdgcn_rcpf(1.0f + e);
}
__device__ __forceinline__ float ftanh(float x) {
    float e = __expf(-2.0f * x);
    return __fmaf_rn(2.0f, __builtin_amdgcn_rcpf(1.0f + e), -1.0f);
}
__device__ __forceinline__ uint32_t pack2bf16(float a, float b) {
    uint32_t ua = __float_as_uint(a) + 0x8000u;
    uint32_t ub = __float_as_uint(b) + 0x8000u;
    return (ua >> 16) | (ub & 0xFFFF0000u);
}

// async global->LDS, 16B/lane; LDS base wave-uniform, lands at lds + lane*16.
__device__ __forceinline__ void gld_lds16(const void* gsrc, void* ldst) {
    __builtin_amdgcn_global_load_lds(
        (const __attribute__((address_space(1))) unsigned int*)gsrc,
        (__attribute__((address_space(3))) unsigned int*)ldst,
        16, 0, 0);
}

// ---------- prep kernels ----------

__global__ void k_transpose_all(const float* __restrict__ s0, float* __restrict__ d0,
                                const float* __restrict__ s1, float* __restrict__ d1,
                                const float* __restrict__ s2, float* __restrict__ d2,
                                const float* __restrict__ s3, float* __restrict__ d3) {
    int i = blockIdx.x * blockDim.x + threadIdx.x;
    if (i < 16384) {
        int r = i >> 7, c = i & 127; d0[c * 128 + r] = s0[i];
    } else if (i < 32768) {
        int j = i - 16384; int r = j >> 7, c = j & 127; d1[c * 128 + r] = s1[j];
    } else if (i < 40960) {
        int j = i - 32768; int r = j >> 7, c = j & 127; d2[c * 64 + r] = s2[j];
    } else if (i < 49152) {
        int j = i - 40960; int r = j >> 7, c = j & 127; d3[c * 64 + r] = s3[j];
    }
}

__global__ void k_cast_bf16(const float* __restrict__ src, ushort* __restrict__ dst, int n) {
    int i = (blockIdx.x * blockDim.x + threadIdx.x) * 4;
    if (i + 3 < n) {
        float4 v = *(const float4*)(src + i);
        uint2 d; d.x = pack2bf16(v.x, v.y); d.y = pack2bf16(v.z, v.w);
        *(uint2*)(dst + i) = d;
    } else {
        for (int k = i; k < n; ++k)
            dst[k] = (ushort)((__float_as_uint(src[k]) + 0x8000u) >> 16);
    }
}

// Pack all 4 [512 x 128] weights into MFMA B-fragment order.
// ih (which 0,2): 32x32x16 layout (consumed by k_xu).
// hh (which 1,3): 16x16x32 layout (consumed by k_lstm_rec9):
//   frag[((g*8+w)*4+ks)*64 + lane]; jj = g*128+w*16+(lane&15), k = ks*32+(lane>>4)*8+j.
__global__ void k_pack_all(const float* __restrict__ w0, u32x4* __restrict__ f0,
                           const float* __restrict__ w1, u32x4* __restrict__ f1,
                           const float* __restrict__ w2, u32x4* __restrict__ f2,
                           const float* __restrict__ w3, u32x4* __restrict__ f3) {
    int gt = blockIdx.x * 256 + threadIdx.x;     // 0..32767
    int which = gt >> 13;
    int tid  = gt & 8191;
    const float* wsrc = (which == 0) ? w0 : (which == 1) ? w1 : (which == 2) ? w2 : w3;
    u32x4* frag = (which == 0) ? f0 : (which == 1) ? f1 : (which == 2) ? f2 : f3;
    int lane = tid & 63;
    float v[8];
    if ((which & 1) == 0) {
        // 32x32x16 B-frag (k_xu)
        int tile = (tid >> 6) & 15;
        int kst  = tid >> 10;
        int n     = tile * 32 + (lane & 31);
        int kbase = kst * 16 + (lane >> 5) * 8;
#pragma unroll
        for (int j = 0; j < 8; ++j) v[j] = wsrc[n * 128 + kbase + j];
    } else {
        // 16x16x32 B-frag (k_lstm_rec9)
        int f  = tid >> 6;            // 0..127
        int ks = f & 3;
        int w8 = (f >> 2) & 7;
        int g  = f >> 5;
        int jj    = g * 128 + w8 * 16 + (lane & 15);
        int kbase = ks * 32 + (lane >> 4) * 8;
#pragma unroll
        for (int j = 0; j < 8; ++j) v[j] = wsrc[jj * 128 + kbase + j];
    }
    u32x4 d;
    d.x = pack2bf16(v[0], v[1]);
    d.y = pack2bf16(v[2], v[3]);
    d.z = pack2bf16(v[4], v[5]);
    d.w = pack2bf16(v[6], v[7]);
    frag[tid] = d;
}

// ---------- kernel A: Xu = x @ W_ih^T + (b_ih+b_hh), gate-quad row store ----------
__global__ __launch_bounds__(256, 2) void k_xu(
    const ushort* __restrict__ x,       // [N,128] bf16
    const u32x4*  __restrict__ wih,     // 8192 B-frags (32x32 layout)
    const float*  __restrict__ b_ih,    // [512]
    const float*  __restrict__ b_hh,    // [512]
    u32x2*        __restrict__ xu,      // [Nceil][128] u32x2 (1KB rows)
    int N)
{
    __shared__ u32x4 a_buf[16][66];

    const int tid   = threadIdx.x;
    const int lane  = tid & 63;
    const int w     = tid >> 6;
    const int mrow  = lane & 31;
    const int khalf = lane >> 5;
    const int node0 = blockIdx.x * 64;

    u32x4 wreg[8][4];
#pragma unroll
    for (int kst = 0; kst < 8; ++kst)
#pragma unroll
        for (int g = 0; g < 4; ++g)
            wreg[kst][g] = wih[(kst * 16 + g * 4 + w) * 64 + lane];

    float binit[4];
#pragma unroll
    for (int g = 0; g < 4; ++g) {
        int jj = g * 128 + w * 32 + mrow;
        binit[g] = b_ih[jj] + b_hh[jj];
    }

    {
        int m_st = tid >> 2, c4 = tid & 3;
        int gn = node0 + m_st; if (gn >= N) gn = N - 1;
        const u32x4* src = (const u32x4*)(x + (size_t)gn * IN);
#pragma unroll
        for (int q = 0; q < 4; ++q) {
            int kg = q * 4 + c4;
            a_buf[kg][m_st] = src[kg];
        }
    }
    __syncthreads();

    const int coff = w * 32 + mrow;
#pragma unroll 1
    for (int Mt = 0; Mt < 2; ++Mt) {
        f32x16 acc[4];
#pragma unroll
        for (int g = 0; g < 4; ++g)
#pragma unroll
            for (int r = 0; r < 16; ++r) acc[g][r] = binit[g];

#pragma unroll
        for (int kst = 0; kst < 8; ++kst) {
            bf16x8 a = __builtin_bit_cast(bf16x8, a_buf[kst * 2 + khalf][Mt * 32 + mrow]);
#pragma unroll
            for (int g = 0; g < 4; ++g)
                acc[g] = __builtin_amdgcn_mfma_f32_32x32x16_bf16(
                    a, __builtin_bit_cast(bf16x8, wreg[kst][g]), acc[g], 0, 0, 0);
        }

#pragma unroll
        for (int r = 0; r < 16; ++r) {
            int m = Mt * 32 + (r & 3) + 8 * (r >> 2) + 4 * khalf;
            u32x2 d;
            d.x = pack2bf16(acc[0][r], acc[1][r]);
            d.y = pack2bf16(acc[2][r], acc[3][r]);
            xu[(size_t)(node0 + m) * 128 + coff] = d;
        }
    }
}

// ---------- kernel B: recurrent LSTM, 8-wave 16-col slices + staged prefetch ----------
// wave w owns channels [w*16, w*16+16) of ALL 4 gates for 32 nodes.
// acc layout (16x16 C): node m = mt*16 + (lane>>4)*4 + q, ch = w*16 + (lane&15).
// Per step: 32 rows x 1KB xu staged in LDS (dbuf), issued 1 step ahead via
// global_load_lds (wave w stages row k*8+w, lane*16 covers the row).
__global__ __launch_bounds__(512, 4) void k_lstm_rec9(
    const u32x2* __restrict__ xu,       // 1KB gate-quad rows
    const int*   __restrict__ nbr,      // [N,16]
    const u32x4* __restrict__ whh,      // 128 B-frags (16x16 layout)
    ushort*      __restrict__ h_out,    // [N,128] bf16
    int N)
{
    __shared__ alignas(16) u32x4  stage[2][32 * 64];   // 2 x 32KB
    __shared__ alignas(16) ushort h_lds[32 * IN];      // 8KB, XOR-swizzled
    __shared__ alignas(16) int    idxs[DEG * 32];      // 2KB [t][m]
    // total 74KB -> 2 blocks/CU at (512,4)

    const int tid  = threadIdx.x;
    const int lane = tid & 63;
    const int w    = tid >> 6;        // 0..7 channel block
    const int col  = lane & 15;
    const int l4   = lane >> 4;       // 0..3
    const int node0 = blockIdx.x * 32;

    {   // idxs[t*32+m], one per thread
        int m = tid & 31, t = tid >> 5;
        int gn = node0 + m; if (gn >= N) gn = N - 1;
        idxs[t * 32 + m] = nbr[gn * DEG + t];
    }
    // zero h(-1): 512 threads x 16B = 8KB
    ((u32x4*)h_lds)[tid] = u32x4{0u, 0u, 0u, 0u};

    __syncthreads();   // idxs visible for staging

    // prologue: stage step 0 into stage[0]
#pragma unroll
    for (int k = 0; k < 4; ++k) {
        int row = k * 8 + w;
        const char* src = (const char*)xu + (size_t)(uint32_t)idxs[row] * 1024u;
        gld_lds16(src + lane * 16, (void*)&stage[0][row * 64]);
    }

    // W_hh fragments: 64 VGPRs (overlaps with stage-0 latency)
    u32x4 wreg[4][4];
#pragma unroll
    for (int g = 0; g < 4; ++g)
#pragma unroll
        for (int ks = 0; ks < 4; ++ks)
            wreg[g][ks] = whh[((g * 8 + w) * 4 + ks) * 64 + lane];

    float cst[8];
#pragma unroll
    for (int r = 0; r < 8; ++r) cst[r] = 0.0f;

    const uint32_t cwb  = (uint32_t)(w * 32 + col * 2);   // h-write ch byte (even lanes)
    const uint32_t aswz = ((uint32_t)(col & 7)) << 4;     // A-read row swizzle

    __syncthreads();   // drains stage-0 loads; h zeros visible

#pragma unroll 1
    for (int t = 0; t < DEG; ++t) {
        const char* st = (const char*)&stage[t & 1][0];

        // ---- prefetch step t+1 into the other stage slot (drained at barrier B2)
        if (t + 1 < DEG) {
#pragma unroll
            for (int k = 0; k < 4; ++k) {
                int row = k * 8 + w;
                const char* src = (const char*)xu +
                    (size_t)(uint32_t)idxs[(t + 1) * 32 + row] * 1024u;
                gld_lds16(src + lane * 16, (void*)&stage[(t + 1) & 1][row * 64]);
            }
        }

        // ---- acc init from staged xu (conflict-free ds_read_b64)
        f32x4 acc[4][2];
#pragma unroll
        for (int mt = 0; mt < 2; ++mt)
#pragma unroll
            for (int q = 0; q < 4; ++q) {
                int m = mt * 16 + l4 * 4 + q;
                u32x2 p = *(const u32x2*)(st + m * 1024 + w * 128 + col * 8);
                acc[0][mt][q] = __uint_as_float(p.x << 16);
                acc[1][mt][q] = __uint_as_float(p.x & 0xFFFF0000u);
                acc[2][mt][q] = __uint_as_float(p.y << 16);
                acc[3][mt][q] = __uint_as_float(p.y & 0xFFFF0000u);
            }

        // ---- MFMA: A = h(t-1) from swizzled LDS, B = wreg
#pragma unroll
        for (int ks = 0; ks < 4; ++ks) {
            const uint32_t ab = ((uint32_t)(ks * 64 + l4 * 16)) ^ aswz;
            bf16x8 a0 = *(const bf16x8*)((const char*)h_lds + col * 256 + ab);
            bf16x8 a1 = *(const bf16x8*)((const char*)h_lds + 4096 + col * 256 + ab);
#pragma unroll
            for (int g = 0; g < 4; ++g) {
                acc[g][0] = __builtin_amdgcn_mfma_f32_16x16x32_bf16(
                    a0, __builtin_bit_cast(bf16x8, wreg[g][ks]), acc[g][0], 0, 0, 0);
                acc[g][1] = __builtin_amdgcn_mfma_f32_16x16x32_bf16(
                    a1, __builtin_bit_cast(bf16x8, wreg[g][ks]), acc[g][1], 0, 0, 0);
            }
        }

        // ---- cell update (registers only)
        float hv[8];
#pragma unroll
        for (int mt = 0; mt < 2; ++mt)
#pragma unroll
            for (int q = 0; q < 4; ++q) {
                int r = mt * 4 + q;
                float iv = fsigmoid(acc[0][mt][q]);
                float fv = fsigmoid(acc[1][mt][q]);
                float gv = ftanh(acc[2][mt][q]);
                float ov = fsigmoid(acc[3][mt][q]);
                float cv = __fmaf_rn(fv, cst[r], iv * gv);
                cst[r] = cv;
                hv[r] = ov * ftanh(cv);
            }

        __syncthreads();   // B1: all reads of h(t-1) + stage[t] done (h single-buffered)

        // ---- h(t) write: shfl-pack pairs, u32 stores by even lanes (2-way = free)
#pragma unroll
        for (int mt = 0; mt < 2; ++mt)
#pragma unroll
            for (int q = 0; q < 4; ++q) {
                int r = mt * 4 + q;
                int m = mt * 16 + l4 * 4 + q;
                uint32_t hb = __float_as_uint(hv[r]) + 0x8000u;
                uint32_t pb = (uint32_t)__shfl_xor((int)hb, 1, 64);
                if ((lane & 1) == 0) {
                    uint32_t bo = (uint32_t)(m * 256) +
                                  (cwb ^ (((uint32_t)(m & 7)) << 4));
                    *(uint32_t*)((char*)h_lds + bo) = (hb >> 16) | (pb & 0xFFFF0000u);
                }
            }

        __syncthreads();   // B2: h(t) visible; drains prefetch -> stage[(t+1)&1] ready
    }

    // ---- writeout: h(15) in h_lds
    {
        int m = tid >> 4, c16 = tid & 15;
        int gn = node0 + m;
        if (gn < N) {
            u32x4 val = *(const u32x4*)((const char*)h_lds + m * 256 +
                                        (((uint32_t)(c16 * 16)) ^ (((uint32_t)(m & 7)) << 4)));
            *(u32x4*)(h_out + (size_t)gn * IN + c16 * 8) = val;
        }
    }
}

// ---------- output linear (fp32 math, bf16 inputs) ----------

template <int NOUT, int ACT, typename OutT>
__global__ __launch_bounds__(256) void k_out_linear(
    const ushort* __restrict__ x, const ushort* __restrict__ h,
    const float* __restrict__ wTs, const float* __restrict__ wTn,
    const float* __restrict__ bias, OutT* __restrict__ out, int N)
{
    constexpr int NPS = 32 / (256 / NOUT);
    __shared__ alignas(16) float x_lds[32][IN];
    __shared__ alignas(16) float h_lds[32][IN];

    const int tid  = threadIdx.x;
    const int j    = tid % NOUT;
    const int slot = tid / NOUT;
    const int node0 = blockIdx.x * 32;

    for (int i = tid; i < 32 * (IN / 8); i += 256) {
        int n = i >> 4, u4 = i & 15;
        int gn = node0 + n; if (gn >= N) gn = N - 1;
        u32x4 xv = *(const u32x4*)(x + (size_t)gn * IN + u4 * 8);
        u32x4 hv = *(const u32x4*)(h + (size_t)gn * IN + u4 * 8);
        float* xd = &x_lds[n][u4 * 8];
        float* hd = &h_lds[n][u4 * 8];
        xd[0] = __uint_as_float(xv.x << 16); xd[1] = __uint_as_float(xv.x & 0xFFFF0000u);
        xd[2] = __uint_as_float(xv.y << 16); xd[3] = __uint_as_float(xv.y & 0xFFFF0000u);
        xd[4] = __uint_as_float(xv.z << 16); xd[5] = __uint_as_float(xv.z & 0xFFFF0000u);
        xd[6] = __uint_as_float(xv.w << 16); xd[7] = __uint_as_float(xv.w & 0xFFFF0000u);
        hd[0] = __uint_as_float(hv.x << 16); hd[1] = __uint_as_float(hv.x & 0xFFFF0000u);
        hd[2] = __uint_as_float(hv.y << 16); hd[3] = __uint_as_float(hv.y & 0xFFFF0000u);
        hd[4] = __uint_as_float(hv.z << 16); hd[5] = __uint_as_float(hv.z & 0xFFFF0000u);
        hd[6] = __uint_as_float(hv.w << 16); hd[7] = __uint_as_float(hv.w & 0xFFFF0000u);
    }
    __syncthreads();

    float acc[NPS];
    const float bj = bias[j];
#pragma unroll
    for (int n = 0; n < NPS; ++n) acc[n] = bj;

#pragma unroll 2
    for (int k = 0; k < IN; ++k) {
        const float ws = wTs[k * NOUT + j];
        const float wn = wTn[k * NOUT + j];
#pragma unroll
        for (int n = 0; n < NPS; ++n) {
            acc[n] = __fmaf_rn(x_lds[slot * NPS + n][k], ws,
                     __fmaf_rn(h_lds[slot * NPS + n][k], wn, acc[n]));
        }
    }

#pragma unroll
    for (int n = 0; n < NPS; ++n) {
        int gn = node0 + slot * NPS + n;
        if (gn < N) {
            float v = acc[n];
            v = (ACT == 0) ? fmaxf(v, 0.0f) : fsigmoid(v);
            if constexpr (sizeof(OutT) == 2)
                out[(size_t)gn * NOUT + j] = (OutT)((__float_as_uint(v) + 0x8000u) >> 16);
            else
                out[(size_t)gn * NOUT + j] = v;
        }
    }
}

extern "C" void kernel_launch(void* const* d_in, const int* in_sizes, int n_in,
                              void* d_out, int out_size, void* d_ws, size_t ws_size,
                              hipStream_t stream)
{
    const float* feats    = (const float*)d_in[0];
    const int*   nbr      = (const int*)  d_in[1];
    const float* w_ih1    = (const float*)d_in[2];
    const float* w_hh1    = (const float*)d_in[3];
    const float* b_ih1    = (const float*)d_in[4];
    const float* b_hh1    = (const float*)d_in[5];
    const float* w_self1  = (const float*)d_in[6];
    const float* w_neigh1 = (const float*)d_in[7];
    const float* b1       = (const float*)d_in[8];
    const float* w_ih2    = (const float*)d_in[9];
    const float* w_hh2    = (const float*)d_in[10];
    const float* b_ih2    = (const float*)d_in[11];
    const float* b_hh2    = (const float*)d_in[12];
    const float* w_self2  = (const float*)d_in[13];
    const float* w_neigh2 = (const float*)d_in[14];
    const float* b2       = (const float*)d_in[15];
    float* out = (float*)d_out;

    const int N = in_sizes[0] / IN;   // 50000
    const long long Nceil = (N + 63) & ~63LL;

    char* ws = (char*)d_ws;
    size_t off = 0;
    auto alloc = [&](size_t bytes) -> void* {
        void* p = (void*)(ws + off);
        off += (bytes + 255) & ~(size_t)255;
        return p;
    };
    u32x4*  wfrag_ih1 = (u32x4*)alloc(8192 * 16);
    u32x4*  wfrag_hh1 = (u32x4*)alloc(8192 * 16);
    u32x4*  wfrag_ih2 = (u32x4*)alloc(8192 * 16);
    u32x4*  wfrag_hh2 = (u32x4*)alloc(8192 * 16);
    float*  wT_self1  = (float*)alloc(128 * 128 * 4);
    float*  wT_neigh1 = (float*)alloc(128 * 128 * 4);
    float*  wT_self2  = (float*)alloc(64 * 128 * 4);
    float*  wT_neigh2 = (float*)alloc(64 * 128 * 4);
    ushort* feats_bf  = (ushort*)alloc((size_t)N * 128 * 2);
    ushort* h_buf     = (ushort*)alloc((size_t)N * 128 * 2);
    ushort* out1      = (ushort*)alloc((size_t)N * 128 * 2);
    u32x2*  xu_buf    = (u32x2*)alloc((size_t)Nceil * 128 * 8);   // 51.25MB

    // prep (fused)
    k_pack_all<<<dim3(128), dim3(256), 0, stream>>>(w_ih1, wfrag_ih1, w_hh1, wfrag_hh1,
                                                    w_ih2, wfrag_ih2, w_hh2, wfrag_hh2);
    k_transpose_all<<<dim3(192), dim3(256), 0, stream>>>(w_self1, wT_self1, w_neigh1, wT_neigh1,
                                                         w_self2, wT_self2, w_neigh2, wT_neigh2);
    k_cast_bf16<<<dim3((N * 128 / 4 + 255) / 256), dim3(256), 0, stream>>>(feats, feats_bf, N * 128);

    const int nblk64 = (int)(Nceil / 64);
    const int nblk32 = (N + 31) / 32;

    // layer 1
    k_xu<<<dim3(nblk64), dim3(256), 0, stream>>>(feats_bf, wfrag_ih1, b_ih1, b_hh1, xu_buf, N);
    k_lstm_rec9<<<dim3(nblk32), dim3(512), 0, stream>>>(xu_buf, nbr, wfrag_hh1, h_buf, N);
    k_out_linear<128, 0, ushort><<<dim3(nblk32), dim3(256), 0, stream>>>(feats_bf, h_buf, wT_self1, wT_neigh1, b1, out1, N);

    // layer 2
    k_xu<<<dim3(nblk64), dim3(256), 0, stream>>>(out1, wfrag_ih2, b_ih2, b_hh2, xu_buf, N);
    k_lstm_rec9<<<dim3(nblk32), dim3(512), 0, stream>>>(xu_buf, nbr, wfrag_hh2, h_buf, N);
    k_out_linear<64, 1, float><<<dim3(nblk32), dim3(256), 0, stream>>>(out1, h_buf, wT_self2, wT_neigh2, b2, out, N);
}

// Round 4
// 795.024 us; speedup vs baseline: 1.3953x; 1.3953x over previous
//
#include <hip/hip_runtime.h>
#include <cstdint>
#include <cstddef>

// SAGE-LSTM R15: 8-wave decomposition, spill-free at (512,4).
// R13/R14 post-mortem: WRITE_SIZE 69/94 MB vs 12.8 MB of real stores = scratch
// spill. gfx950 unified VGPR+AGPR file: (512,4) budget = 128 TOTAL regs;
// wreg(64)+acc(32)+misc blew it. VGPR_Count=64 is arch-only (64+64 AGPR = 128).
// R15 fixes the budget: sequential M-tiles (acc 32->16), direct global->reg
// gather with 1-step-ahead register prefetch (16 regs), h as padded A-frags
// [32][17] u32x4 (R11's proven 0-conflict pattern), double-buffered -> 1
// barrier/step. Tally: 64+16+16+8+~15 = ~119 <= 128. LDS only 19.5KB.

constexpr int IN  = 128;
constexpr int DEG = 16;

typedef short bf16x8 __attribute__((ext_vector_type(8)));
typedef float f32x4  __attribute__((ext_vector_type(4)));
typedef float f32x16 __attribute__((ext_vector_type(16)));
typedef unsigned int u32x4 __attribute__((ext_vector_type(4)));
typedef unsigned int u32x2 __attribute__((ext_vector_type(2)));

__device__ __forceinline__ float fsigmoid(float x) {
    float e = __expf(-x);
    return __builtin_amdgcn_rcpf(1.0f + e);
}
__device__ __forceinline__ float ftanh(float x) {
    float e = __expf(-2.0f * x);
    return __fmaf_rn(2.0f, __builtin_amdgcn_rcpf(1.0f + e), -1.0f);
}
__device__ __forceinline__ uint32_t pack2bf16(float a, float b) {
    uint32_t ua = __float_as_uint(a) + 0x8000u;
    uint32_t ub = __float_as_uint(b) + 0x8000u;
    return (ua >> 16) | (ub & 0xFFFF0000u);
}

// ---------- prep kernels ----------

__global__ void k_transpose_all(const float* __restrict__ s0, float* __restrict__ d0,
                                const float* __restrict__ s1, float* __restrict__ d1,
                                const float* __restrict__ s2, float* __restrict__ d2,
                                const float* __restrict__ s3, float* __restrict__ d3) {
    int i = blockIdx.x * blockDim.x + threadIdx.x;
    if (i < 16384) {
        int r = i >> 7, c = i & 127; d0[c * 128 + r] = s0[i];
    } else if (i < 32768) {
        int j = i - 16384; int r = j >> 7, c = j & 127; d1[c * 128 + r] = s1[j];
    } else if (i < 40960) {
        int j = i - 32768; int r = j >> 7, c = j & 127; d2[c * 64 + r] = s2[j];
    } else if (i < 49152) {
        int j = i - 40960; int r = j >> 7, c = j & 127; d3[c * 64 + r] = s3[j];
    }
}

__global__ void k_cast_bf16(const float* __restrict__ src, ushort* __restrict__ dst, int n) {
    int i = (blockIdx.x * blockDim.x + threadIdx.x) * 4;
    if (i + 3 < n) {
        float4 v = *(const float4*)(src + i);
        uint2 d; d.x = pack2bf16(v.x, v.y); d.y = pack2bf16(v.z, v.w);
        *(uint2*)(dst + i) = d;
    } else {
        for (int k = i; k < n; ++k)
            dst[k] = (ushort)((__float_as_uint(src[k]) + 0x8000u) >> 16);
    }
}

// Pack all 4 [512 x 128] weights into MFMA B-fragment order.
// ih (which 0,2): 32x32x16 layout (consumed by k_xu).
// hh (which 1,3): 16x16x32 layout (consumed by k_lstm_rec10):
//   frag[((g*8+w)*4+ks)*64 + lane]; jj = g*128+w*16+(lane&15), k = ks*32+(lane>>4)*8+j.
__global__ void k_pack_all(const float* __restrict__ w0, u32x4* __restrict__ f0,
                           const float* __restrict__ w1, u32x4* __restrict__ f1,
                           const float* __restrict__ w2, u32x4* __restrict__ f2,
                           const float* __restrict__ w3, u32x4* __restrict__ f3) {
    int gt = blockIdx.x * 256 + threadIdx.x;     // 0..32767
    int which = gt >> 13;
    int tid  = gt & 8191;
    const float* wsrc = (which == 0) ? w0 : (which == 1) ? w1 : (which == 2) ? w2 : w3;
    u32x4* frag = (which == 0) ? f0 : (which == 1) ? f1 : (which == 2) ? f2 : f3;
    int lane = tid & 63;
    float v[8];
    if ((which & 1) == 0) {
        // 32x32x16 B-frag (k_xu)
        int tile = (tid >> 6) & 15;
        int kst  = tid >> 10;
        int n     = tile * 32 + (lane & 31);
        int kbase = kst * 16 + (lane >> 5) * 8;
#pragma unroll
        for (int j = 0; j < 8; ++j) v[j] = wsrc[n * 128 + kbase + j];
    } else {
        // 16x16x32 B-frag (k_lstm_rec10)
        int f  = tid >> 6;            // 0..127
        int ks = f & 3;
        int w8 = (f >> 2) & 7;
        int g  = f >> 5;
        int jj    = g * 128 + w8 * 16 + (lane & 15);
        int kbase = ks * 32 + (lane >> 4) * 8;
#pragma unroll
        for (int j = 0; j < 8; ++j) v[j] = wsrc[jj * 128 + kbase + j];
    }
    u32x4 d;
    d.x = pack2bf16(v[0], v[1]);
    d.y = pack2bf16(v[2], v[3]);
    d.z = pack2bf16(v[4], v[5]);
    d.w = pack2bf16(v[6], v[7]);
    frag[tid] = d;
}

// ---------- kernel A: Xu = x @ W_ih^T + (b_ih+b_hh), gate-quad row store ----------
__global__ __launch_bounds__(256, 2) void k_xu(
    const ushort* __restrict__ x,       // [N,128] bf16
    const u32x4*  __restrict__ wih,     // 8192 B-frags (32x32 layout)
    const float*  __restrict__ b_ih,    // [512]
    const float*  __restrict__ b_hh,    // [512]
    u32x2*        __restrict__ xu,      // [Nceil][128] u32x2 (1KB rows)
    int N)
{
    __shared__ u32x4 a_buf[16][66];

    const int tid   = threadIdx.x;
    const int lane  = tid & 63;
    const int w     = tid >> 6;
    const int mrow  = lane & 31;
    const int khalf = lane >> 5;
    const int node0 = blockIdx.x * 64;

    u32x4 wreg[8][4];
#pragma unroll
    for (int kst = 0; kst < 8; ++kst)
#pragma unroll
        for (int g = 0; g < 4; ++g)
            wreg[kst][g] = wih[(kst * 16 + g * 4 + w) * 64 + lane];

    float binit[4];
#pragma unroll
    for (int g = 0; g < 4; ++g) {
        int jj = g * 128 + w * 32 + mrow;
        binit[g] = b_ih[jj] + b_hh[jj];
    }

    {
        int m_st = tid >> 2, c4 = tid & 3;
        int gn = node0 + m_st; if (gn >= N) gn = N - 1;
        const u32x4* src = (const u32x4*)(x + (size_t)gn * IN);
#pragma unroll
        for (int q = 0; q < 4; ++q) {
            int kg = q * 4 + c4;
            a_buf[kg][m_st] = src[kg];
        }
    }
    __syncthreads();

    const int coff = w * 32 + mrow;
#pragma unroll 1
    for (int Mt = 0; Mt < 2; ++Mt) {
        f32x16 acc[4];
#pragma unroll
        for (int g = 0; g < 4; ++g)
#pragma unroll
            for (int r = 0; r < 16; ++r) acc[g][r] = binit[g];

#pragma unroll
        for (int kst = 0; kst < 8; ++kst) {
            bf16x8 a = __builtin_bit_cast(bf16x8, a_buf[kst * 2 + khalf][Mt * 32 + mrow]);
#pragma unroll
            for (int g = 0; g < 4; ++g)
                acc[g] = __builtin_amdgcn_mfma_f32_32x32x16_bf16(
                    a, __builtin_bit_cast(bf16x8, wreg[kst][g]), acc[g], 0, 0, 0);
        }

#pragma unroll
        for (int r = 0; r < 16; ++r) {
            int m = Mt * 32 + (r & 3) + 8 * (r >> 2) + 4 * khalf;
            u32x2 d;
            d.x = pack2bf16(acc[0][r], acc[1][r]);
            d.y = pack2bf16(acc[2][r], acc[3][r]);
            xu[(size_t)(node0 + m) * 128 + coff] = d;
        }
    }
}

// ---------- kernel B: recurrent LSTM, 8-wave 16-col slices, spill-free ----------
// wave w owns channels [w*16, w*16+16) of ALL 4 gates for 32 nodes.
// acc (16x16 C): node m = mt*16 + l4*4 + q, ch = w*16 + col; tiles mt sequential.
// h stored as padded 16x16x32 A-frags: h_frag[buf][node*17 + ks*4 + l4] u32x4;
// 17 = 16+1 pad => A-reads 8 lanes/bank-group (optimal), writes 2-way (free).
__global__ __launch_bounds__(512, 4) void k_lstm_rec10(
    const u32x2* __restrict__ xu,       // 1KB gate-quad rows
    const int*   __restrict__ nbr,      // [N,16]
    const u32x4* __restrict__ whh,      // 128 B-frags (16x16 layout)
    ushort*      __restrict__ h_out,    // [N,128] bf16
    int N)
{
    __shared__ alignas(16) u32x4 h_frag[2][32 * 17];   // 2 x 8.5KB padded
    __shared__ alignas(16) int   idxs[DEG * 32];       // 2KB [t][m]

    const int tid  = threadIdx.x;
    const int lane = tid & 63;
    const int w    = tid >> 6;        // 0..7 channel block
    const int col  = lane & 15;
    const int l4   = lane >> 4;       // 0..3
    const int node0 = blockIdx.x * 32;

    {   // idxs[t*32+m], one per thread
        int m = tid & 31, t = tid >> 5;
        int gn = node0 + m; if (gn >= N) gn = N - 1;
        idxs[t * 32 + m] = nbr[gn * DEG + t];
    }
    // zero h(-1) = buf[0] (544 entries)
    h_frag[0][tid] = u32x4{0u, 0u, 0u, 0u};
    if (tid < 32) h_frag[0][512 + tid] = u32x4{0u, 0u, 0u, 0u};

    // W_hh fragments: 64 regs (AGPR side of unified file)
    u32x4 wreg[4][4];
#pragma unroll
    for (int g = 0; g < 4; ++g)
#pragma unroll
        for (int ks = 0; ks < 4; ++ks)
            wreg[g][ks] = whh[((g * 8 + w) * 4 + ks) * 64 + lane];

    float cst[8];
#pragma unroll
    for (int r = 0; r < 8; ++r) cst[r] = 0.0f;

    const char* xu_c = (const char*)xu;
    const uint32_t lanebyte = (uint32_t)(w * 128 + col * 8);  // this wave's slice

    __syncthreads();   // idxs + zeros visible

    // prologue: gather step-0 xu gate-quads into registers
    u32x2 v[8];
    {
        const int4 i0 = *(const int4*)&idxs[l4 * 4];
        const int4 i1 = *(const int4*)&idxs[16 + l4 * 4];
        v[0] = *(const u32x2*)(xu_c + (size_t)((uint32_t)i0.x * 1024u + lanebyte));
        v[1] = *(const u32x2*)(xu_c + (size_t)((uint32_t)i0.y * 1024u + lanebyte));
        v[2] = *(const u32x2*)(xu_c + (size_t)((uint32_t)i0.z * 1024u + lanebyte));
        v[3] = *(const u32x2*)(xu_c + (size_t)((uint32_t)i0.w * 1024u + lanebyte));
        v[4] = *(const u32x2*)(xu_c + (size_t)((uint32_t)i1.x * 1024u + lanebyte));
        v[5] = *(const u32x2*)(xu_c + (size_t)((uint32_t)i1.y * 1024u + lanebyte));
        v[6] = *(const u32x2*)(xu_c + (size_t)((uint32_t)i1.z * 1024u + lanebyte));
        v[7] = *(const u32x2*)(xu_c + (size_t)((uint32_t)i1.w * 1024u + lanebyte));
    }

#pragma unroll 1
    for (int t = 0; t < DEG; ++t) {
        const u32x4* hr = &h_frag[t & 1][0];
        u32x4*       hw = &h_frag[(t + 1) & 1][0];

#pragma unroll
        for (int mt = 0; mt < 2; ++mt) {
            // ---- acc init from gathered xu (consumes v[mt*4 .. mt*4+3])
            f32x4 acc[4];
#pragma unroll
            for (int q = 0; q < 4; ++q) {
                u32x2 p = v[mt * 4 + q];
                acc[0][q] = __uint_as_float(p.x << 16);
                acc[1][q] = __uint_as_float(p.x & 0xFFFF0000u);
                acc[2][q] = __uint_as_float(p.y << 16);
                acc[3][q] = __uint_as_float(p.y & 0xFFFF0000u);
            }

            // ---- after v fully consumed (mt==1): prefetch step t+1 into v.
            // Latency (~900cyc L2/L3) hides under tile-1 MFMA+cell (+barrier).
            if (mt == 1 && t + 1 < DEG) {
                const int4 i0 = *(const int4*)&idxs[(t + 1) * 32 + l4 * 4];
                const int4 i1 = *(const int4*)&idxs[(t + 1) * 32 + 16 + l4 * 4];
                v[0] = *(const u32x2*)(xu_c + (size_t)((uint32_t)i0.x * 1024u + lanebyte));
                v[1] = *(const u32x2*)(xu_c + (size_t)((uint32_t)i0.y * 1024u + lanebyte));
                v[2] = *(const u32x2*)(xu_c + (size_t)((uint32_t)i0.z * 1024u + lanebyte));
                v[3] = *(const u32x2*)(xu_c + (size_t)((uint32_t)i0.w * 1024u + lanebyte));
                v[4] = *(const u32x2*)(xu_c + (size_t)((uint32_t)i1.x * 1024u + lanebyte));
                v[5] = *(const u32x2*)(xu_c + (size_t)((uint32_t)i1.y * 1024u + lanebyte));
                v[6] = *(const u32x2*)(xu_c + (size_t)((uint32_t)i1.z * 1024u + lanebyte));
                v[7] = *(const u32x2*)(xu_c + (size_t)((uint32_t)i1.w * 1024u + lanebyte));
            }

            // ---- MFMA: A = h(t-1) frags from padded LDS, B = wreg
#pragma unroll
            for (int ks = 0; ks < 4; ++ks) {
                bf16x8 a = __builtin_bit_cast(bf16x8,
                    hr[(mt * 16 + col) * 17 + ks * 4 + l4]);
#pragma unroll
                for (int g = 0; g < 4; ++g)
                    acc[g] = __builtin_amdgcn_mfma_f32_16x16x32_bf16(
                        a, __builtin_bit_cast(bf16x8, wreg[g][ks]), acc[g], 0, 0, 0);
            }

            // ---- cell update + packed h-write (A-frag layout, pad 17)
#pragma unroll
            for (int q = 0; q < 4; ++q) {
                int r = mt * 4 + q;
                float iv = fsigmoid(acc[0][q]);
                float fv = fsigmoid(acc[1][q]);
                float gv = ftanh(acc[2][q]);
                float ov = fsigmoid(acc[3][q]);
                float cv = __fmaf_rn(fv, cst[r], iv * gv);
                cst[r] = cv;
                float hv = ov * ftanh(cv);
                int m = mt * 16 + l4 * 4 + q;
                uint32_t hb = __float_as_uint(hv) + 0x8000u;
                uint32_t pb = (uint32_t)__shfl_xor((int)hb, 1, 64);
                if ((lane & 1) == 0) {
                    // ch = w*16+col (col even): u32 covers ch,ch+1
                    int du = (m * 17 + w * 2 + (col >> 3)) * 4 + ((col & 7) >> 1);
                    ((uint32_t*)hw)[du] = (hb >> 16) | (pb & 0xFFFF0000u);
                }
            }
        }

        __syncthreads();   // h(t) visible; WAR-safe via dbuf (1 barrier/step)
    }

    // ---- writeout: h(15) lives in buf[16&1] = buf[0]
    {
        int m = tid >> 4, c16 = tid & 15;
        int gn = node0 + m;
        if (gn < N) {
            u32x4 val = h_frag[0][m * 17 + c16];
            *(u32x4*)(h_out + (size_t)gn * IN + c16 * 8) = val;
        }
    }
}

// ---------- output linear (fp32 math, bf16 inputs) ----------

template <int NOUT, int ACT, typename OutT>
__global__ __launch_bounds__(256) void k_out_linear(
    const ushort* __restrict__ x, const ushort* __restrict__ h,
    const float* __restrict__ wTs, const float* __restrict__ wTn,
    const float* __restrict__ bias, OutT* __restrict__ out, int N)
{
    constexpr int NPS = 32 / (256 / NOUT);
    __shared__ alignas(16) float x_lds[32][IN];
    __shared__ alignas(16) float h_lds[32][IN];

    const int tid  = threadIdx.x;
    const int j    = tid % NOUT;
    const int slot = tid / NOUT;
    const int node0 = blockIdx.x * 32;

    for (int i = tid; i < 32 * (IN / 8); i += 256) {
        int n = i >> 4, u4 = i & 15;
        int gn = node0 + n; if (gn >= N) gn = N - 1;
        u32x4 xv = *(const u32x4*)(x + (size_t)gn * IN + u4 * 8);
        u32x4 hv = *(const u32x4*)(h + (size_t)gn * IN + u4 * 8);
        float* xd = &x_lds[n][u4 * 8];
        float* hd = &h_lds[n][u4 * 8];
        xd[0] = __uint_as_float(xv.x << 16); xd[1] = __uint_as_float(xv.x & 0xFFFF0000u);
        xd[2] = __uint_as_float(xv.y << 16); xd[3] = __uint_as_float(xv.y & 0xFFFF0000u);
        xd[4] = __uint_as_float(xv.z << 16); xd[5] = __uint_as_float(xv.z & 0xFFFF0000u);
        xd[6] = __uint_as_float(xv.w << 16); xd[7] = __uint_as_float(xv.w & 0xFFFF0000u);
        hd[0] = __uint_as_float(hv.x << 16); hd[1] = __uint_as_float(hv.x & 0xFFFF0000u);
        hd[2] = __uint_as_float(hv.y << 16); hd[3] = __uint_as_float(hv.y & 0xFFFF0000u);
        hd[4] = __uint_as_float(hv.z << 16); hd[5] = __uint_as_float(hv.z & 0xFFFF0000u);
        hd[6] = __uint_as_float(hv.w << 16); hd[7] = __uint_as_float(hv.w & 0xFFFF0000u);
    }
    __syncthreads();

    float acc[NPS];
    const float bj = bias[j];
#pragma unroll
    for (int n = 0; n < NPS; ++n) acc[n] = bj;

#pragma unroll 2
    for (int k = 0; k < IN; ++k) {
        const float ws = wTs[k * NOUT + j];
        const float wn = wTn[k * NOUT + j];
#pragma unroll
        for (int n = 0; n < NPS; ++n) {
            acc[n] = __fmaf_rn(x_lds[slot * NPS + n][k], ws,
                     __fmaf_rn(h_lds[slot * NPS + n][k], wn, acc[n]));
        }
    }

#pragma unroll
    for (int n = 0; n < NPS; ++n) {
        int gn = node0 + slot * NPS + n;
        if (gn < N) {
            float v = acc[n];
            v = (ACT == 0) ? fmaxf(v, 0.0f) : fsigmoid(v);
            if constexpr (sizeof(OutT) == 2)
                out[(size_t)gn * NOUT + j] = (OutT)((__float_as_uint(v) + 0x8000u) >> 16);
            else
                out[(size_t)gn * NOUT + j] = v;
        }
    }
}

extern "C" void kernel_launch(void* const* d_in, const int* in_sizes, int n_in,
                              void* d_out, int out_size, void* d_ws, size_t ws_size,
                              hipStream_t stream)
{
    const float* feats    = (const float*)d_in[0];
    const int*   nbr      = (const int*)  d_in[1];
    const float* w_ih1    = (const float*)d_in[2];
    const float* w_hh1    = (const float*)d_in[3];
    const float* b_ih1    = (const float*)d_in[4];
    const float* b_hh1    = (const float*)d_in[5];
    const float* w_self1  = (const float*)d_in[6];
    const float* w_neigh1 = (const float*)d_in[7];
    const float* b1       = (const float*)d_in[8];
    const float* w_ih2    = (const float*)d_in[9];
    const float* w_hh2    = (const float*)d_in[10];
    const float* b_ih2    = (const float*)d_in[11];
    const float* b_hh2    = (const float*)d_in[12];
    const float* w_self2  = (const float*)d_in[13];
    const float* w_neigh2 = (const float*)d_in[14];
    const float* b2       = (const float*)d_in[15];
    float* out = (float*)d_out;

    const int N = in_sizes[0] / IN;   // 50000
    const long long Nceil = (N + 63) & ~63LL;

    char* ws = (char*)d_ws;
    size_t off = 0;
    auto alloc = [&](size_t bytes) -> void* {
        void* p = (void*)(ws + off);
        off += (bytes + 255) & ~(size_t)255;
        return p;
    };
    u32x4*  wfrag_ih1 = (u32x4*)alloc(8192 * 16);
    u32x4*  wfrag_hh1 = (u32x4*)alloc(8192 * 16);
    u32x4*  wfrag_ih2 = (u32x4*)alloc(8192 * 16);
    u32x4*  wfrag_hh2 = (u32x4*)alloc(8192 * 16);
    float*  wT_self1  = (float*)alloc(128 * 128 * 4);
    float*  wT_neigh1 = (float*)alloc(128 * 128 * 4);
    float*  wT_self2  = (float*)alloc(64 * 128 * 4);
    float*  wT_neigh2 = (float*)alloc(64 * 128 * 4);
    ushort* feats_bf  = (ushort*)alloc((size_t)N * 128 * 2);
    ushort* h_buf     = (ushort*)alloc((size_t)N * 128 * 2);
    ushort* out1      = (ushort*)alloc((size_t)N * 128 * 2);
    u32x2*  xu_buf    = (u32x2*)alloc((size_t)Nceil * 128 * 8);   // 51.25MB

    // prep (fused)
    k_pack_all<<<dim3(128), dim3(256), 0, stream>>>(w_ih1, wfrag_ih1, w_hh1, wfrag_hh1,
                                                    w_ih2, wfrag_ih2, w_hh2, wfrag_hh2);
    k_transpose_all<<<dim3(192), dim3(256), 0, stream>>>(w_self1, wT_self1, w_neigh1, wT_neigh1,
                                                         w_self2, wT_self2, w_neigh2, wT_neigh2);
    k_cast_bf16<<<dim3((N * 128 / 4 + 255) / 256), dim3(256), 0, stream>>>(feats, feats_bf, N * 128);

    const int nblk64 = (int)(Nceil / 64);
    const int nblk32 = (N + 31) / 32;

    // layer 1
    k_xu<<<dim3(nblk64), dim3(256), 0, stream>>>(feats_bf, wfrag_ih1, b_ih1, b_hh1, xu_buf, N);
    k_lstm_rec10<<<dim3(nblk32), dim3(512), 0, stream>>>(xu_buf, nbr, wfrag_hh1, h_buf, N);
    k_out_linear<128, 0, ushort><<<dim3(nblk32), dim3(256), 0, stream>>>(feats_bf, h_buf, wT_self1, wT_neigh1, b1, out1, N);

    // layer 2
    k_xu<<<dim3(nblk64), dim3(256), 0, stream>>>(out1, wfrag_ih2, b_ih2, b_hh2, xu_buf, N);
    k_lstm_rec10<<<dim3(nblk32), dim3(512), 0, stream>>>(xu_buf, nbr, wfrag_hh2, h_buf, N);
    k_out_linear<64, 1, float><<<dim3(nblk32), dim3(256), 0, stream>>>(out1, h_buf, wT_self2, wT_neigh2, b2, out, N);
}

// Round 5
// 536.500 us; speedup vs baseline: 2.0677x; 1.4819x over previous
//
#include <hip/hip_runtime.h>
#include <cstdint>
#include <cstddef>

// SAGE-LSTM R16: C^T operand swap + fused output-linear epilogue.
// R15 post-mortem: 74% combined issue occupancy -> instruction-bound, not
// stall-bound. R16 removes instructions:
//  (1) mfma(W,h) computes C^T: lane owns 4 ADJACENT channels x 1 node ->
//      h-write pack needs no shfl_xor (saves 8 DS + ~16 VALU/thread/step);
//      xu gather = 4x16B contiguous loads; idxs pre-scaled to byte offsets.
//      A/B frags are lane-symmetric -> zero repack changes for W_hh/h.
//  (2) out-linear fused as MFMA epilogue over K=256 ([x|h] @ [Ws;Wn]^T):
//      kills 2 fp32-VALU dispatches, k_transpose_all, and the 25.6MB h_buf
//      round-trip. h is already in LDS in B-frag layout.

constexpr int IN  = 128;
constexpr int DEG = 16;

typedef short bf16x8 __attribute__((ext_vector_type(8)));
typedef float f32x4  __attribute__((ext_vector_type(4)));
typedef float f32x16 __attribute__((ext_vector_type(16)));
typedef unsigned int u32x4 __attribute__((ext_vector_type(4)));
typedef unsigned int u32x2 __attribute__((ext_vector_type(2)));

__device__ __forceinline__ float fsigmoid(float x) {
    float e = __expf(-x);
    return __builtin_amdgcn_rcpf(1.0f + e);
}
__device__ __forceinline__ float ftanh(float x) {
    float e = __expf(-2.0f * x);
    return __fmaf_rn(2.0f, __builtin_amdgcn_rcpf(1.0f + e), -1.0f);
}
__device__ __forceinline__ uint32_t pack2bf16(float a, float b) {
    uint32_t ua = __float_as_uint(a) + 0x8000u;
    uint32_t ub = __float_as_uint(b) + 0x8000u;
    return (ua >> 16) | (ub & 0xFFFF0000u);
}

// ---------- prep kernels ----------

__global__ void k_cast_bf16(const float* __restrict__ src, ushort* __restrict__ dst, int n) {
    int i = (blockIdx.x * blockDim.x + threadIdx.x) * 4;
    if (i + 3 < n) {
        float4 v = *(const float4*)(src + i);
        uint2 d; d.x = pack2bf16(v.x, v.y); d.y = pack2bf16(v.z, v.w);
        *(uint2*)(dst + i) = d;
    } else {
        for (int k = i; k < n; ++k)
            dst[k] = (ushort)((__float_as_uint(src[k]) + 0x8000u) >> 16);
    }
}

// Pack all 4 [512 x 128] gate weights into MFMA fragment order.
// ih (which 0,2): 32x32x16 B-frag (consumed by k_xu).
// hh (which 1,3): 16x16x32 frag (A-operand in k_lstm_fused):
//   frag[((g*8+w)*4+ks)*64 + lane]; row jj = g*128+w*16+(lane&15),
//   k = ks*32+(lane>>4)*8+j.  (A and B frag layouts are lane-symmetric.)
__global__ void k_pack_all(const float* __restrict__ w0, u32x4* __restrict__ f0,
                           const float* __restrict__ w1, u32x4* __restrict__ f1,
                           const float* __restrict__ w2, u32x4* __restrict__ f2,
                           const float* __restrict__ w3, u32x4* __restrict__ f3) {
    int gt = blockIdx.x * 256 + threadIdx.x;     // 0..32767
    int which = gt >> 13;
    int tid  = gt & 8191;
    const float* wsrc = (which == 0) ? w0 : (which == 1) ? w1 : (which == 2) ? w2 : w3;
    u32x4* frag = (which == 0) ? f0 : (which == 1) ? f1 : (which == 2) ? f2 : f3;
    int lane = tid & 63;
    float v[8];
    if ((which & 1) == 0) {
        int tile = (tid >> 6) & 15;
        int kst  = tid >> 10;
        int n     = tile * 32 + (lane & 31);
        int kbase = kst * 16 + (lane >> 5) * 8;
#pragma unroll
        for (int j = 0; j < 8; ++j) v[j] = wsrc[n * 128 + kbase + j];
    } else {
        int f  = tid >> 6;            // 0..127
        int ks = f & 3;
        int w8 = (f >> 2) & 7;
        int g  = f >> 5;
        int jj    = g * 128 + w8 * 16 + (lane & 15);
        int kbase = ks * 32 + (lane >> 4) * 8;
#pragma unroll
        for (int j = 0; j < 8; ++j) v[j] = wsrc[jj * 128 + kbase + j];
    }
    u32x4 d;
    d.x = pack2bf16(v[0], v[1]);
    d.y = pack2bf16(v[2], v[3]);
    d.z = pack2bf16(v[4], v[5]);
    d.w = pack2bf16(v[6], v[7]);
    frag[tid] = d;
}

// Pack output-linear weights as A-frags over K=256 concat [Wself ; Wneigh].
// L1: f1[(w*8+ks)*64+lane], och = w*16+(lane&15), k = ks*32+(lane>>4)*8+j.
// L2: f2[(c*8+ks)*64+lane], och = c*16+(lane&15)  (64 out chs, c=0..3).
__global__ void k_pack_out(const float* __restrict__ ws1, const float* __restrict__ wn1,
                           u32x4* __restrict__ f1,
                           const float* __restrict__ ws2, const float* __restrict__ wn2,
                           u32x4* __restrict__ f2) {
    int t = blockIdx.x * 256 + threadIdx.x;   // 0..6143
    int lane = t & 63;
    int row  = lane & 15;
    int kb   = (lane >> 4) * 8;
    float v[8];
    const float* ws; const float* wn; u32x4* dst; int p;
    if (t < 4096) { ws = ws1; wn = wn1; dst = f1; p = t; }
    else          { ws = ws2; wn = wn2; dst = f2; p = t - 4096; }
    int ks  = (p >> 6) & 7;
    int och = (p >> 9) * 16 + row;
    int kbase = ks * 32 + kb;
#pragma unroll
    for (int j = 0; j < 8; ++j) {
        int k = kbase + j;
        v[j] = (k < 128) ? ws[och * 128 + k] : wn[och * 128 + k - 128];
    }
    u32x4 d;
    d.x = pack2bf16(v[0], v[1]);
    d.y = pack2bf16(v[2], v[3]);
    d.z = pack2bf16(v[4], v[5]);
    d.w = pack2bf16(v[6], v[7]);
    dst[p] = d;
}

// ---------- kernel A: Xu = x @ W_ih^T + (b_ih+b_hh), gate-quad row store ----------
__global__ __launch_bounds__(256, 2) void k_xu(
    const ushort* __restrict__ x,       // [N,128] bf16
    const u32x4*  __restrict__ wih,     // 8192 B-frags (32x32 layout)
    const float*  __restrict__ b_ih,    // [512]
    const float*  __restrict__ b_hh,    // [512]
    u32x2*        __restrict__ xu,      // [Nceil][128] u32x2 (1KB rows)
    int N)
{
    __shared__ u32x4 a_buf[16][66];

    const int tid   = threadIdx.x;
    const int lane  = tid & 63;
    const int w     = tid >> 6;
    const int mrow  = lane & 31;
    const int khalf = lane >> 5;
    const int node0 = blockIdx.x * 64;

    u32x4 wreg[8][4];
#pragma unroll
    for (int kst = 0; kst < 8; ++kst)
#pragma unroll
        for (int g = 0; g < 4; ++g)
            wreg[kst][g] = wih[(kst * 16 + g * 4 + w) * 64 + lane];

    float binit[4];
#pragma unroll
    for (int g = 0; g < 4; ++g) {
        int jj = g * 128 + w * 32 + mrow;
        binit[g] = b_ih[jj] + b_hh[jj];
    }

    {
        int m_st = tid >> 2, c4 = tid & 3;
        int gn = node0 + m_st; if (gn >= N) gn = N - 1;
        const u32x4* src = (const u32x4*)(x + (size_t)gn * IN);
#pragma unroll
        for (int q = 0; q < 4; ++q) {
            int kg = q * 4 + c4;
            a_buf[kg][m_st] = src[kg];
        }
    }
    __syncthreads();

    const int coff = w * 32 + mrow;
#pragma unroll 1
    for (int Mt = 0; Mt < 2; ++Mt) {
        f32x16 acc[4];
#pragma unroll
        for (int g = 0; g < 4; ++g)
#pragma unroll
            for (int r = 0; r < 16; ++r) acc[g][r] = binit[g];

#pragma unroll
        for (int kst = 0; kst < 8; ++kst) {
            bf16x8 a = __builtin_bit_cast(bf16x8, a_buf[kst * 2 + khalf][Mt * 32 + mrow]);
#pragma unroll
            for (int g = 0; g < 4; ++g)
                acc[g] = __builtin_amdgcn_mfma_f32_32x32x16_bf16(
                    a, __builtin_bit_cast(bf16x8, wreg[kst][g]), acc[g], 0, 0, 0);
        }

#pragma unroll
        for (int r = 0; r < 16; ++r) {
            int m = Mt * 32 + (r & 3) + 8 * (r >> 2) + 4 * khalf;
            u32x2 d;
            d.x = pack2bf16(acc[0][r], acc[1][r]);
            d.y = pack2bf16(acc[2][r], acc[3][r]);
            xu[(size_t)(node0 + m) * 128 + coff] = d;
        }
    }
}

// ---------- kernel B: recurrent LSTM (C^T) + fused output linear ----------
// wave w owns channels [w*16,w*16+16) of ALL 4 gates; C^T: row = channel
// (l4*4+q), col = node. Lane owns 4 ADJACENT channels of 1 node per tile ->
// shfl-free h pack. h LDS: [node][ch] bf16, row stride 272B (17x16B).
template <int NOUT, int ACT, typename OutT>
__global__ __launch_bounds__(512, 4) void k_lstm_fused(
    const u32x2*  __restrict__ xu,      // 1KB gate-quad rows
    const int*    __restrict__ nbr,     // [N,16]
    const u32x4*  __restrict__ whh,     // 128 frags (A-operand)
    const u32x4*  __restrict__ wout,    // epilogue A-frags (K=256 concat)
    const float*  __restrict__ bout,    // [NOUT]
    const ushort* __restrict__ x_in,    // [N,128] bf16 (self input)
    OutT*         __restrict__ out,     // [N,NOUT]
    int N)
{
    constexpr int HSTR = 272;                        // 17 x 16B, b128-aligned
    __shared__ alignas(16) char h_lds[2][32 * HSTR]; // 2 x 8.5KB
    __shared__ uint32_t idxs[DEG * 32];              // prescaled byte offsets

    const int tid  = threadIdx.x;
    const int lane = tid & 63;
    const int w    = tid >> 6;
    const int col  = lane & 15;
    const int l4   = lane >> 4;
    const int node0 = blockIdx.x * 32;

    {
        int m = tid & 31, t = tid >> 5;
        int gn = node0 + m; if (gn >= N) gn = N - 1;
        idxs[t * 32 + m] = (uint32_t)nbr[gn * DEG + t] << 10;
    }
    for (int i = tid; i < 32 * HSTR / 16; i += 512)
        ((u32x4*)h_lds[0])[i] = u32x4{0u, 0u, 0u, 0u};

    // W_hh A-frags: 64 regs
    u32x4 wreg[4][4];
#pragma unroll
    for (int g = 0; g < 4; ++g)
#pragma unroll
        for (int ks = 0; ks < 4; ++ks)
            wreg[g][ks] = whh[((g * 8 + w) * 4 + ks) * 64 + lane];

    float cst[8];
#pragma unroll
    for (int r = 0; r < 8; ++r) cst[r] = 0.0f;

    const char* xu_c = (const char*)xu;
    const uint32_t goff = (uint32_t)(w * 128 + l4 * 32);  // slice byte in xu row
    const int rd0 = col * HSTR + l4 * 16;                 // + ks*64 + mt*16*HSTR
    const int wr0 = col * HSTR + w * 32 + l4 * 8;         // + mt*16*HSTR

    __syncthreads();   // idxs + h(-1) zeros visible

    // prologue gather (step 0): 32B contiguous per (node, ch-quad)
    u32x4 vv[4];
    {
        const char* p0 = xu_c + idxs[col] + goff;
        const char* p1 = xu_c + idxs[16 + col] + goff;
        vv[0] = *(const u32x4*)(p0);
        vv[1] = *(const u32x4*)(p0 + 16);
        vv[2] = *(const u32x4*)(p1);
        vv[3] = *(const u32x4*)(p1 + 16);
    }

#pragma unroll 1
    for (int t = 0; t < DEG; ++t) {
        const char* hr = h_lds[t & 1];
        char*       hw = h_lds[(t + 1) & 1];

#pragma unroll
        for (int mt = 0; mt < 2; ++mt) {
            // ---- acc init: C^T element (ch = w*16+l4*4+q, node = mt*16+col)
            f32x4 acc[4];
#pragma unroll
            for (int q = 0; q < 4; ++q) {
                uint32_t px = vv[mt * 2 + (q >> 1)][(q & 1) * 2];
                uint32_t py = vv[mt * 2 + (q >> 1)][(q & 1) * 2 + 1];
                acc[0][q] = __uint_as_float(px << 16);
                acc[1][q] = __uint_as_float(px & 0xFFFF0000u);
                acc[2][q] = __uint_as_float(py << 16);
                acc[3][q] = __uint_as_float(py & 0xFFFF0000u);
            }

            // ---- prefetch next step once vv fully consumed
            if (mt == 1 && t + 1 < DEG) {
                const char* p0 = xu_c + idxs[(t + 1) * 32 + col] + goff;
                const char* p1 = xu_c + idxs[(t + 1) * 32 + 16 + col] + goff;
                vv[0] = *(const u32x4*)(p0);
                vv[1] = *(const u32x4*)(p0 + 16);
                vv[2] = *(const u32x4*)(p1);
                vv[3] = *(const u32x4*)(p1 + 16);
            }

            // ---- MFMA C^T: A = W_hh frags, B = h(t-1) from LDS
#pragma unroll
            for (int ks = 0; ks < 4; ++ks) {
                bf16x8 b = *(const bf16x8*)(hr + mt * 16 * HSTR + rd0 + ks * 64);
#pragma unroll
                for (int g = 0; g < 4; ++g)
                    acc[g] = __builtin_amdgcn_mfma_f32_16x16x32_bf16(
                        __builtin_bit_cast(bf16x8, wreg[g][ks]), b, acc[g], 0, 0, 0);
            }

            // ---- cell update + shfl-free packed h write (4 adjacent chs)
            float hv[4];
#pragma unroll
            for (int q = 0; q < 4; ++q) {
                int r = mt * 4 + q;
                float iv = fsigmoid(acc[0][q]);
                float fv = fsigmoid(acc[1][q]);
                float gv = ftanh(acc[2][q]);
                float ov = fsigmoid(acc[3][q]);
                float cv = __fmaf_rn(fv, cst[r], iv * gv);
                cst[r] = cv;
                hv[q] = ov * ftanh(cv);
            }
            u32x2 hp;
            hp.x = pack2bf16(hv[0], hv[1]);
            hp.y = pack2bf16(hv[2], hv[3]);
            *(u32x2*)(hw + mt * 16 * HSTR + wr0) = hp;
        }

        __syncthreads();   // h(t) visible; WAR-safe via dbuf (1 barrier/step)
    }

    // ---- fused output linear: out = act([x|h] @ [Ws;Wn]^T + b), C^T MFMA
    {
        const char* hf = h_lds[0];                 // h(15) parity: buf[16&1]
        constexpr int TILES = (NOUT == 128) ? 2 : 1;
        const int otile = (NOUT == 128) ? w : (w & 3);
        const int mtb   = (NOUT == 128) ? 0 : (w >> 2);
        const int och0  = otile * 16 + l4 * 4;
        const float4 bq = *(const float4*)(bout + och0);

#pragma unroll
        for (int mi = 0; mi < TILES; ++mi) {
            const int mt = mtb + mi;
            const int gn = node0 + mt * 16 + col;
            const int gx = (gn < N) ? gn : (N - 1);
            f32x4 acc = {bq.x, bq.y, bq.z, bq.w};
#pragma unroll
            for (int ks = 0; ks < 8; ++ks) {
                u32x4 af = wout[(otile * 8 + ks) * 64 + lane];
                bf16x8 bf_;
                if (ks < 4)
                    bf_ = *(const bf16x8*)((const char*)x_in + (size_t)gx * 256 +
                                           ks * 64 + l4 * 16);
                else
                    bf_ = *(const bf16x8*)(hf + mt * 16 * HSTR + col * HSTR +
                                           (ks - 4) * 64 + l4 * 16);
                acc = __builtin_amdgcn_mfma_f32_16x16x32_bf16(
                    __builtin_bit_cast(bf16x8, af), bf_, acc, 0, 0, 0);
            }
            if (gn < N) {
                float av[4];
#pragma unroll
                for (int q = 0; q < 4; ++q)
                    av[q] = (ACT == 0) ? fmaxf(acc[q], 0.0f) : fsigmoid(acc[q]);
                if constexpr (sizeof(OutT) == 2) {
                    u32x2 o;
                    o.x = pack2bf16(av[0], av[1]);
                    o.y = pack2bf16(av[2], av[3]);
                    *(u32x2*)((ushort*)out + (size_t)gn * NOUT + och0) = o;
                } else {
                    f32x4 o = {av[0], av[1], av[2], av[3]};
                    *(f32x4*)((float*)out + (size_t)gn * NOUT + och0) = o;
                }
            }
        }
    }
}

extern "C" void kernel_launch(void* const* d_in, const int* in_sizes, int n_in,
                              void* d_out, int out_size, void* d_ws, size_t ws_size,
                              hipStream_t stream)
{
    const float* feats    = (const float*)d_in[0];
    const int*   nbr      = (const int*)  d_in[1];
    const float* w_ih1    = (const float*)d_in[2];
    const float* w_hh1    = (const float*)d_in[3];
    const float* b_ih1    = (const float*)d_in[4];
    const float* b_hh1    = (const float*)d_in[5];
    const float* w_self1  = (const float*)d_in[6];
    const float* w_neigh1 = (const float*)d_in[7];
    const float* b1       = (const float*)d_in[8];
    const float* w_ih2    = (const float*)d_in[9];
    const float* w_hh2    = (const float*)d_in[10];
    const float* b_ih2    = (const float*)d_in[11];
    const float* b_hh2    = (const float*)d_in[12];
    const float* w_self2  = (const float*)d_in[13];
    const float* w_neigh2 = (const float*)d_in[14];
    const float* b2       = (const float*)d_in[15];
    float* out = (float*)d_out;

    const int N = in_sizes[0] / IN;   // 50000
    const long long Nceil = (N + 63) & ~63LL;

    char* ws = (char*)d_ws;
    size_t off = 0;
    auto alloc = [&](size_t bytes) -> void* {
        void* p = (void*)(ws + off);
        off += (bytes + 255) & ~(size_t)255;
        return p;
    };
    u32x4*  wfrag_ih1 = (u32x4*)alloc(8192 * 16);
    u32x4*  wfrag_hh1 = (u32x4*)alloc(8192 * 16);
    u32x4*  wfrag_ih2 = (u32x4*)alloc(8192 * 16);
    u32x4*  wfrag_hh2 = (u32x4*)alloc(8192 * 16);
    u32x4*  wofrag1   = (u32x4*)alloc(4096 * 16);   // 64KB epilogue A-frags L1
    u32x4*  wofrag2   = (u32x4*)alloc(2048 * 16);   // 32KB epilogue A-frags L2
    ushort* feats_bf  = (ushort*)alloc((size_t)N * 128 * 2);
    ushort* out1      = (ushort*)alloc((size_t)N * 128 * 2);
    u32x2*  xu_buf    = (u32x2*)alloc((size_t)Nceil * 128 * 8);   // 51.25MB

    // prep
    k_pack_all<<<dim3(128), dim3(256), 0, stream>>>(w_ih1, wfrag_ih1, w_hh1, wfrag_hh1,
                                                    w_ih2, wfrag_ih2, w_hh2, wfrag_hh2);
    k_pack_out<<<dim3(24), dim3(256), 0, stream>>>(w_self1, w_neigh1, wofrag1,
                                                   w_self2, w_neigh2, wofrag2);
    k_cast_bf16<<<dim3((N * 128 / 4 + 255) / 256), dim3(256), 0, stream>>>(feats, feats_bf, N * 128);

    const int nblk64 = (int)(Nceil / 64);
    const int nblk32 = (N + 31) / 32;

    // layer 1
    k_xu<<<dim3(nblk64), dim3(256), 0, stream>>>(feats_bf, wfrag_ih1, b_ih1, b_hh1, xu_buf, N);
    k_lstm_fused<128, 0, ushort><<<dim3(nblk32), dim3(512), 0, stream>>>(
        xu_buf, nbr, wfrag_hh1, wofrag1, b1, feats_bf, out1, N);

    // layer 2
    k_xu<<<dim3(nblk64), dim3(256), 0, stream>>>(out1, wfrag_ih2, b_ih2, b_hh2, xu_buf, N);
    k_lstm_fused<64, 1, float><<<dim3(nblk32), dim3(512), 0, stream>>>(
        xu_buf, nbr, wfrag_hh2, wofrag2, b2, out1, out, N);
}